// Round 4
// baseline (274.264 us; speedup 1.0000x reference)
//
#include <hip/hip_runtime.h>

// MultiGaussSpatialConv: B=1, N=M=8192, D=3, C=16, fp32.
// out[n,c] = sum_i w_i * (sum_m e_i(n,m) yf[m,c]) / (sum_m e_i(n,m))
// e_i = exp(-d2/(2 s^2)), 1/(2 s^2) = {200, 50, 12.5} -> e0 = e2^16, e1 = e2^4.
//
// R4 (= R3 with the cvt_pkrtz vector-element type fixed via __fp16 union):
//  - fp16 MFMA (e and yf quantized to fp16; e-quantization cancels exactly in
//    the num/den ratio, only yf quantization ~2^-11 |f| survives).
//  - per-block LDS staging of yf->fp16 B-fragments (no prep kernel).
//  - split-K tail reduction via agent-scope sentinel flags in ws (no reduce
//    kernel; ws is re-poisoned 0xAA per call so SENT != poison needs no memset).

static constexpr int Nn = 8192;
static constexpr int Mm = 8192;
static constexpr int NF = 52;                     // 48 num + 3 den + 1 pad
static constexpr unsigned int SENT = 0x5EEDF00Du;

typedef _Float16 half8 __attribute__((ext_vector_type(8)));
typedef __fp16  fp16x2 __attribute__((ext_vector_type(2)));
typedef float  float4v __attribute__((ext_vector_type(4)));

#define MFMA_F16 __builtin_amdgcn_mfma_f32_16x16x32_f16

__global__ __launch_bounds__(256) void mgsc_one(
    const float* __restrict__ x, const float* __restrict__ y,
    const float* __restrict__ yf, float* part, unsigned int* flags,
    float* __restrict__ out, int nchunks)
{
    // fragS: fp16 B-fragments for a 512-m tile, exact per-lane read order:
    //   idx(m_loc, c) = (m_loc>>5)*512 + (((m_loc&31)>>3)*16 + c)*8 + (m_loc&7)
    __shared__ __align__(16) _Float16 fragS[512 * 16];   // 16 KB
    __shared__ __align__(16) float qS[512 * 4];          // 8 KB (yx,yy,yz,|y|^2)

    const int tid  = threadIdx.x;
    const int wave = tid >> 6, lane = tid & 63;
    const int g    = lane >> 4, c = lane & 15;
    const int xb   = blockIdx.x, yb = blockIdx.y;
    const int mc   = Mm / nchunks;                 // multiple of 512
    const int ntile = xb * 64 + wave * 16;
    const int nrow  = ntile + c;                   // A-frag row for this lane

    const float xx = x[3 * nrow], xy = x[3 * nrow + 1], xz = x[3 * nrow + 2];
    const float x2 = xx * xx + xy * xy + xz * xz;

    float4v acc0 = {0.f, 0.f, 0.f, 0.f}, acc1 = acc0, acc2 = acc0;
    float4v dac0 = acc0, dac1 = acc0, dac2 = acc0;

    const _Float16 onev = (c == 0) ? (_Float16)1.0f : (_Float16)0.0f;
    half8 bone = {onev, onev, onev, onev, onev, onev, onev, onev};

    for (int sm = 0; sm < mc; sm += 512) {
        const int m0 = yb * mc + sm;
        __syncthreads();                            // protect prior tile reads
#pragma unroll
        for (int it = 0; it < 2; ++it) {
            const int ml = tid + it * 256;          // local m 0..511
            const int m  = m0 + ml;
            const float ax = y[3 * m], ay = y[3 * m + 1], az = y[3 * m + 2];
            reinterpret_cast<float4*>(qS)[ml] =
                make_float4(ax, ay, az, ax * ax + ay * ay + az * az);
            const float4* fr = reinterpret_cast<const float4*>(yf + (size_t)m * 16);
            float4 f[4];
            f[0] = fr[0]; f[1] = fr[1]; f[2] = fr[2]; f[3] = fr[3];
            const float* ff = reinterpret_cast<const float*>(f);
            _Float16* dst = fragS + ((ml >> 5) << 9) + (((ml & 31) >> 3) << 7) + (ml & 7);
#pragma unroll
            for (int cc = 0; cc < 16; ++cc) dst[cc * 8] = (_Float16)ff[cc]; // RNE
        }
        __syncthreads();

        for (int kt = 0; kt < 16; ++kt) {
            const float4* qp = reinterpret_cast<const float4*>(qS) + (kt << 5) + (g << 3);
            float E0[8], E1[8], E2[8];
#pragma unroll
            for (int j = 0; j < 8; ++j) {
                const float4 Q = qp[j];             // LDS broadcast (wave-uniform per g)
                const float p  = __fmaf_rn(xz, Q.z, __fmaf_rn(xy, Q.y, xx * Q.x));
                const float d2 = fmaxf(__fmaf_rn(-2.f, p, x2 + Q.w), 0.f);
                const float e2 = __expf(-12.5f * d2);     // sigma 0.2
                const float t2 = e2 * e2;
                const float e1 = t2 * t2;                 // sigma 0.1  (e2^4)
                const float u2 = e1 * e1;
                const float e0 = u2 * u2;                 // sigma 0.05 (e2^16)
                E0[j] = e0; E1[j] = e1; E2[j] = e2;
            }
            union { fp16x2 h2[4]; half8 v; } A0, A1, A2;
#pragma unroll
            for (int jj = 0; jj < 4; ++jj) {
                A0.h2[jj] = __builtin_amdgcn_cvt_pkrtz(E0[2 * jj], E0[2 * jj + 1]);
                A1.h2[jj] = __builtin_amdgcn_cvt_pkrtz(E1[2 * jj], E1[2 * jj + 1]);
                A2.h2[jj] = __builtin_amdgcn_cvt_pkrtz(E2[2 * jj], E2[2 * jj + 1]);
            }
            const half8 B = *reinterpret_cast<const half8*>(fragS + (kt << 9) + (lane << 3));
            acc0 = MFMA_F16(A0.v, B, acc0, 0, 0, 0);
            acc1 = MFMA_F16(A1.v, B, acc1, 0, 0, 0);
            acc2 = MFMA_F16(A2.v, B, acc2, 0, 0, 0);
            dac0 = MFMA_F16(A0.v, bone, dac0, 0, 0, 0);
            dac1 = MFMA_F16(A1.v, bone, dac1, 0, 0, 0);
            dac2 = MFMA_F16(A2.v, bone, dac2, 0, 0, 0);
        }
    }

    // ---- write partials (agent-scope so they reach the coherence point)
    float* wb = part + (size_t)yb * NF * Nn;
#pragma unroll
    for (int r = 0; r < 4; ++r) {
        const int nr = ntile + (g << 2) + r;        // C/D: col=c, row=g*4+r
        __hip_atomic_store(&wb[(0 * 16 + c) * Nn + nr], acc0[r], __ATOMIC_RELAXED, __HIP_MEMORY_SCOPE_AGENT);
        __hip_atomic_store(&wb[(1 * 16 + c) * Nn + nr], acc1[r], __ATOMIC_RELAXED, __HIP_MEMORY_SCOPE_AGENT);
        __hip_atomic_store(&wb[(2 * 16 + c) * Nn + nr], acc2[r], __ATOMIC_RELAXED, __HIP_MEMORY_SCOPE_AGENT);
    }
    if (c == 0) {
#pragma unroll
        for (int r = 0; r < 4; ++r) {
            const int nr = ntile + (g << 2) + r;
            __hip_atomic_store(&wb[48 * Nn + nr], dac0[r], __ATOMIC_RELAXED, __HIP_MEMORY_SCOPE_AGENT);
            __hip_atomic_store(&wb[49 * Nn + nr], dac1[r], __ATOMIC_RELAXED, __HIP_MEMORY_SCOPE_AGENT);
            __hip_atomic_store(&wb[50 * Nn + nr], dac2[r], __ATOMIC_RELAXED, __HIP_MEMORY_SCOPE_AGENT);
        }
    }
    __threadfence();
    __syncthreads();

    if (nchunks > 1) {
        if (yb != 0) {                              // producer: release flag
            if (tid == 0)
                __hip_atomic_store(&flags[xb * nchunks + yb], SENT,
                                   __ATOMIC_RELEASE, __HIP_MEMORY_SCOPE_AGENT);
            return;
        }
        if (tid < nchunks - 1) {                    // reducer: acquire flags
            unsigned int* fp = &flags[xb * nchunks + 1 + tid];
            while (__hip_atomic_load(fp, __ATOMIC_ACQUIRE, __HIP_MEMORY_SCOPE_AGENT) != SENT)
                __builtin_amdgcn_s_sleep(16);
        }
        __syncthreads();
    }

    // ---- tail reduction (block yb==0 only): weight/den first, then nums
    float* rS = qS;                                 // reuse LDS (192 floats)
    if (tid < 192) {
        const int f = tid >> 6, nl = tid & 63;
        const int n = xb * 64 + nl;
        float d = 0.f;
        for (int k = 0; k < nchunks; ++k)
            d += __hip_atomic_load(&part[(size_t)k * NF * Nn + (48 + f) * Nn + n],
                                   __ATOMIC_RELAXED, __HIP_MEMORY_SCOPE_AGENT);
        rS[f * 64 + nl] = (f == 2 ? 0.4f : 0.3f) / d;
    }
    __syncthreads();
#pragma unroll
    for (int it = 0; it < 4; ++it) {
        const int idx = it * 256 + tid;
        const int nl = idx & 63, cc = idx >> 6;
        const int n  = xb * 64 + nl;
        float s0 = 0.f, s1 = 0.f, s2 = 0.f;
        for (int k = 0; k < nchunks; ++k) {
            float* pb = part + (size_t)k * NF * Nn;
            s0 += __hip_atomic_load(&pb[(0 * 16 + cc) * Nn + n], __ATOMIC_RELAXED, __HIP_MEMORY_SCOPE_AGENT);
            s1 += __hip_atomic_load(&pb[(1 * 16 + cc) * Nn + n], __ATOMIC_RELAXED, __HIP_MEMORY_SCOPE_AGENT);
            s2 += __hip_atomic_load(&pb[(2 * 16 + cc) * Nn + n], __ATOMIC_RELAXED, __HIP_MEMORY_SCOPE_AGENT);
        }
        out[(size_t)n * 16 + cc] = s0 * rS[nl] + s1 * rS[64 + nl] + s2 * rS[128 + nl];
    }
}

// ---------------- fused VALU fallback (workspace too small)
__global__ __launch_bounds__(256) void mgsc_fused(
    const float* __restrict__ x, const float* __restrict__ y,
    const float* __restrict__ yf, float* __restrict__ out)
{
    __shared__ float yS[256 * 3];
    __shared__ float yfS[256 * 16];
    const int tid = threadIdx.x;
    const int n   = blockIdx.x * 256 + tid;
    const float xx = x[3 * n], xy = x[3 * n + 1], xz = x[3 * n + 2];
    float a0[16], a1[16], a2[16];
#pragma unroll
    for (int c = 0; c < 16; ++c) { a0[c] = 0.f; a1[c] = 0.f; a2[c] = 0.f; }
    float den0 = 0.f, den1 = 0.f, den2 = 0.f;
    for (int mt = 0; mt < Mm; mt += 256) {
        const float4* ysrc = reinterpret_cast<const float4*>(y + (size_t)mt * 3);
        if (tid < 192) reinterpret_cast<float4*>(yS)[tid] = ysrc[tid];
        const float4* fsrc = reinterpret_cast<const float4*>(yf + (size_t)mt * 16);
#pragma unroll
        for (int k = 0; k < 4; ++k)
            reinterpret_cast<float4*>(yfS)[tid + 256 * k] = fsrc[tid + 256 * k];
        __syncthreads();
        for (int mm = 0; mm < 256; ++mm) {
            const float dx = xx - yS[3 * mm], dy = xy - yS[3 * mm + 1], dz = xz - yS[3 * mm + 2];
            const float d2 = dx * dx + dy * dy + dz * dz;
            const float e2 = __expf(-12.5f * d2);
            const float t = e2 * e2, e1 = t * t, u = e1 * e1, e0 = u * u;
            den0 += e0; den1 += e1; den2 += e2;
            const float4* fr = reinterpret_cast<const float4*>(yfS + mm * 16);
#pragma unroll
            for (int k = 0; k < 4; ++k) {
                const float4 f = fr[k];
                a0[4*k+0] += e0 * f.x; a0[4*k+1] += e0 * f.y; a0[4*k+2] += e0 * f.z; a0[4*k+3] += e0 * f.w;
                a1[4*k+0] += e1 * f.x; a1[4*k+1] += e1 * f.y; a1[4*k+2] += e1 * f.z; a1[4*k+3] += e1 * f.w;
                a2[4*k+0] += e2 * f.x; a2[4*k+1] += e2 * f.y; a2[4*k+2] += e2 * f.z; a2[4*k+3] += e2 * f.w;
            }
        }
        __syncthreads();
    }
    const float r0 = 0.3f / den0, r1 = 0.3f / den1, r2 = 0.4f / den2;
#pragma unroll
    for (int c = 0; c < 16; ++c)
        out[(size_t)n * 16 + c] = a0[c] * r0 + a1[c] * r1 + a2[c] * r2;
}

extern "C" void kernel_launch(void* const* d_in, const int* in_sizes, int n_in,
                              void* d_out, int out_size, void* d_ws, size_t ws_size,
                              hipStream_t stream) {
    const float* x  = (const float*)d_in[0];
    const float* y  = (const float*)d_in[1];
    const float* yf = (const float*)d_in[2];
    float* out = (float*)d_out;

    const size_t chunkB = (size_t)NF * Nn * sizeof(float);   // 1.704 MB
    int nchunks = 16;                                        // mc must be mult of 512
    while (nchunks > 1 &&
           (size_t)nchunks * chunkB + 128 * (size_t)nchunks * 4 > ws_size)
        nchunks >>= 1;
    if ((size_t)nchunks * chunkB + 128 * (size_t)nchunks * 4 > ws_size) {
        mgsc_fused<<<Nn / 256, 256, 0, stream>>>(x, y, yf, out);
        return;
    }

    float* part = (float*)d_ws;
    unsigned int* flags = (unsigned int*)((char*)d_ws + (size_t)nchunks * chunkB);

    dim3 grid(Nn / 64, nchunks);
    mgsc_one<<<grid, 256, 0, stream>>>(x, y, yf, part, flags, out, nchunks);
}

// Round 5
// 100.152 us; speedup vs baseline: 2.7385x; 2.7385x over previous
//
#include <hip/hip_runtime.h>

// MultiGaussSpatialConv: B=1, N=M=8192, D=3, C=16, fp32.
// out[n,c] = sum_i w_i * (sum_m e_i(n,m) yf[m,c]) / (sum_m e_i(n,m))
// e_i = exp(-d2/(2 s^2)), 1/(2 s^2) = {200, 50, 12.5} -> e0 = e2^16, e1 = e2^4.
//
// R5: back to kernel-boundary coherence (R4's device-scope atomics caused 4x
// write amplification + uncached tail loads -> 274us). Structure:
//  - prep kernel: q[m]=(yx,yy,yz,|y|^2), yf -> fp16 B-fragments in global
//    (384 KB, L2-resident; read-only in main).
//  - main kernel: 512 blocks x 16 n-rows; 4 waves split m 4-way; in-block
//    LDS cross-wave reduction (stride 25 -> conflict-free) + direct finalize.
//  - fp16 MFMA: e-quantization cancels in num/den ratio (R4 absmax 1.95e-3).

static constexpr int Nn = 8192;
static constexpr int Mm = 8192;

typedef _Float16 half8 __attribute__((ext_vector_type(8)));
typedef __fp16  fp16x2 __attribute__((ext_vector_type(2)));
typedef float  float4v __attribute__((ext_vector_type(4)));

#define MFMA_F16 __builtin_amdgcn_mfma_f32_16x16x32_f16

// ---------------- prep: q[m] quad + yf -> fp16 fragments (B-layout)
// frag idx(m,c) = (m>>5)*512 + (((m&31)>>3)*16 + c)*8 + (m&7)
__global__ __launch_bounds__(256) void mgsc_prep(
    const float* __restrict__ y, const float* __restrict__ yf,
    float4* __restrict__ q, _Float16* __restrict__ frag)
{
    const int t = blockIdx.x * 256 + threadIdx.x;   // 0 .. Mm*16-1
    const int m = t >> 4, c = t & 15;
    const int idx = ((m >> 5) << 9) + ((((m & 31) >> 3) << 4) + c) * 8 + (m & 7);
    frag[idx] = (_Float16)yf[t];                    // RNE
    if (t < Mm) {
        const float ax = y[3 * t], ay = y[3 * t + 1], az = y[3 * t + 2];
        q[t] = make_float4(ax, ay, az, ax * ax + ay * ay + az * az);
    }
}

// ---------------- main: one block per 16-row n-tile; waves split m 4-way
__global__ __launch_bounds__(256) void mgsc_main(
    const float* __restrict__ x, const float4* __restrict__ q,
    const _Float16* __restrict__ frag, float* __restrict__ out)
{
    __shared__ float redS[3 * 64 * 25];             // stride 25: conflict-free

    const int tid  = threadIdx.x;
    const int wave = tid >> 6, lane = tid & 63;
    const int g    = lane >> 4, c = lane & 15;
    const int n0   = blockIdx.x * 16;
    const int nrow = n0 + c;                        // A-frag row for this lane

    const float xx = x[3 * nrow], xy = x[3 * nrow + 1], xz = x[3 * nrow + 2];
    const float x2 = xx * xx + xy * xy + xz * xz;

    float4v acc0 = {0.f, 0.f, 0.f, 0.f}, acc1 = acc0, acc2 = acc0;
    float4v dac0 = acc0, dac1 = acc0, dac2 = acc0;

    const _Float16 onev = (c == 0) ? (_Float16)1.0f : (_Float16)0.0f;
    half8 bone = {onev, onev, onev, onev, onev, onev, onev, onev};

    const int kt0 = wave * 64;                      // 256 kt total, 64 per wave
    for (int kt = kt0; kt < kt0 + 64; ++kt) {
        const float4* qk = q + (kt << 5) + (g << 3);
        float E0[8], E1[8], E2[8];
#pragma unroll
        for (int j = 0; j < 8; ++j) {
            const float4 Q = qk[j];                 // L1/L2-hot, 4 addrs/wave
            const float p  = __fmaf_rn(xz, Q.z, __fmaf_rn(xy, Q.y, xx * Q.x));
            const float d2 = fmaxf(__fmaf_rn(-2.f, p, x2 + Q.w), 0.f);
            const float e2 = __expf(-12.5f * d2);   // sigma 0.2
            const float t2 = e2 * e2;
            const float e1 = t2 * t2;               // sigma 0.1  (e2^4)
            const float u2 = e1 * e1;
            const float e0 = u2 * u2;               // sigma 0.05 (e2^16)
            E0[j] = e0; E1[j] = e1; E2[j] = e2;
        }
        union { fp16x2 h2[4]; half8 v; } A0, A1, A2;
#pragma unroll
        for (int jj = 0; jj < 4; ++jj) {
            A0.h2[jj] = __builtin_amdgcn_cvt_pkrtz(E0[2 * jj], E0[2 * jj + 1]);
            A1.h2[jj] = __builtin_amdgcn_cvt_pkrtz(E1[2 * jj], E1[2 * jj + 1]);
            A2.h2[jj] = __builtin_amdgcn_cvt_pkrtz(E2[2 * jj], E2[2 * jj + 1]);
        }
        const half8 B = *reinterpret_cast<const half8*>(frag + ((size_t)kt << 9) + (lane << 3));
        acc0 = MFMA_F16(A0.v, B, acc0, 0, 0, 0);
        acc1 = MFMA_F16(A1.v, B, acc1, 0, 0, 0);
        acc2 = MFMA_F16(A2.v, B, acc2, 0, 0, 0);
        dac0 = MFMA_F16(A0.v, bone, dac0, 0, 0, 0);
        dac1 = MFMA_F16(A1.v, bone, dac1, 0, 0, 0);
        dac2 = MFMA_F16(A2.v, bone, dac2, 0, 0, 0);
    }

    // ---- cross-wave reduction via LDS (waves 1-3 stash, wave 0 sums)
    if (wave != 0) {
        float* s = redS + (wave - 1) * 64 * 25 + lane * 25;
#pragma unroll
        for (int r = 0; r < 4; ++r) {
            s[r]      = acc0[r];
            s[4 + r]  = acc1[r];
            s[8 + r]  = acc2[r];
            s[12 + r] = dac0[r];
            s[16 + r] = dac1[r];
            s[20 + r] = dac2[r];
        }
    }
    __syncthreads();
    if (wave != 0) return;

#pragma unroll
    for (int ww = 0; ww < 3; ++ww) {
        const float* s = redS + ww * 64 * 25 + lane * 25;
#pragma unroll
        for (int r = 0; r < 4; ++r) {
            acc0[r] += s[r];
            acc1[r] += s[4 + r];
            acc2[r] += s[8 + r];
            dac0[r] += s[12 + r];
            dac1[r] += s[16 + r];
            dac2[r] += s[20 + r];
        }
    }

    // ---- finalize: den lives in c==0 lanes (col 0); broadcast within group
    const int src = lane & 48;                      // lane g*16 (c==0 of group)
#pragma unroll
    for (int r = 0; r < 4; ++r) {
        const float d0 = __shfl(dac0[r], src);
        const float d1 = __shfl(dac1[r], src);
        const float d2v = __shfl(dac2[r], src);
        const float v = 0.3f * acc0[r] / d0 + 0.3f * acc1[r] / d1 + 0.4f * acc2[r] / d2v;
        const int n = n0 + (g << 2) + r;            // C/D: col=c, row=g*4+r
        out[(size_t)n * 16 + c] = v;
    }
}

// ---------------- fused VALU fallback (workspace too small)
__global__ __launch_bounds__(256) void mgsc_fused(
    const float* __restrict__ x, const float* __restrict__ y,
    const float* __restrict__ yf, float* __restrict__ out)
{
    __shared__ float yS[256 * 3];
    __shared__ float yfS[256 * 16];
    const int tid = threadIdx.x;
    const int n   = blockIdx.x * 256 + tid;
    const float xx = x[3 * n], xy = x[3 * n + 1], xz = x[3 * n + 2];
    float a0[16], a1[16], a2[16];
#pragma unroll
    for (int c = 0; c < 16; ++c) { a0[c] = 0.f; a1[c] = 0.f; a2[c] = 0.f; }
    float den0 = 0.f, den1 = 0.f, den2 = 0.f;
    for (int mt = 0; mt < Mm; mt += 256) {
        const float4* ysrc = reinterpret_cast<const float4*>(y + (size_t)mt * 3);
        if (tid < 192) reinterpret_cast<float4*>(yS)[tid] = ysrc[tid];
        const float4* fsrc = reinterpret_cast<const float4*>(yf + (size_t)mt * 16);
#pragma unroll
        for (int k = 0; k < 4; ++k)
            reinterpret_cast<float4*>(yfS)[tid + 256 * k] = fsrc[tid + 256 * k];
        __syncthreads();
        for (int mm = 0; mm < 256; ++mm) {
            const float dx = xx - yS[3 * mm], dy = xy - yS[3 * mm + 1], dz = xz - yS[3 * mm + 2];
            const float d2 = dx * dx + dy * dy + dz * dz;
            const float e2 = __expf(-12.5f * d2);
            const float t = e2 * e2, e1 = t * t, u = e1 * e1, e0 = u * u;
            den0 += e0; den1 += e1; den2 += e2;
            const float4* fr = reinterpret_cast<const float4*>(yfS + mm * 16);
#pragma unroll
            for (int k = 0; k < 4; ++k) {
                const float4 f = fr[k];
                a0[4*k+0] += e0 * f.x; a0[4*k+1] += e0 * f.y; a0[4*k+2] += e0 * f.z; a0[4*k+3] += e0 * f.w;
                a1[4*k+0] += e1 * f.x; a1[4*k+1] += e1 * f.y; a1[4*k+2] += e1 * f.z; a1[4*k+3] += e1 * f.w;
                a2[4*k+0] += e2 * f.x; a2[4*k+1] += e2 * f.y; a2[4*k+2] += e2 * f.z; a2[4*k+3] += e2 * f.w;
            }
        }
        __syncthreads();
    }
    const float r0 = 0.3f / den0, r1 = 0.3f / den1, r2 = 0.4f / den2;
#pragma unroll
    for (int c = 0; c < 16; ++c)
        out[(size_t)n * 16 + c] = a0[c] * r0 + a1[c] * r1 + a2[c] * r2;
}

extern "C" void kernel_launch(void* const* d_in, const int* in_sizes, int n_in,
                              void* d_out, int out_size, void* d_ws, size_t ws_size,
                              hipStream_t stream) {
    const float* x  = (const float*)d_in[0];
    const float* y  = (const float*)d_in[1];
    const float* yf = (const float*)d_in[2];
    float* out = (float*)d_out;

    const size_t qB    = (size_t)Mm * sizeof(float4);            // 128 KB
    const size_t fragB = (size_t)Mm * 16 * sizeof(_Float16);     // 256 KB
    if (qB + fragB > ws_size) {
        mgsc_fused<<<Nn / 256, 256, 0, stream>>>(x, y, yf, out);
        return;
    }
    float4*   q    = (float4*)d_ws;
    _Float16* frag = (_Float16*)((char*)d_ws + qB);

    mgsc_prep<<<(Mm * 16) / 256, 256, 0, stream>>>(y, yf, q, frag);
    mgsc_main<<<Nn / 16, 256, 0, stream>>>(x, q, frag, out);
}